// Round 6
// baseline (1770.114 us; speedup 1.0000x reference)
//
#include <hip/hip_runtime.h>

#define DD 1024
#define FF 4096
#define LL 24
#define VV 50277
#define NB 1024
#define AG __HIP_MEMORY_SCOPE_AGENT

typedef unsigned u32;
typedef float v4f __attribute__((ext_vector_type(4)));

// ---------------- reductions ----------------

__device__ __forceinline__ float wave_sum(float v) {
#pragma unroll
    for (int o = 32; o > 0; o >>= 1) v += __shfl_xor(v, o, 64);
    return v;
}

__device__ __forceinline__ float block_sum(float v, float* scr) {
    v = wave_sum(v);
    int w = threadIdx.x >> 6;
    __syncthreads();
    if ((threadIdx.x & 63) == 0) scr[w] = v;
    __syncthreads();
    return scr[0] + scr[1] + scr[2] + scr[3];
}

__device__ __forceinline__ v4f ln_vec(v4f xv, const float* __restrict__ w,
                                      const float* __restrict__ b, float* scr, int t) {
    float m = block_sum(xv[0] + xv[1] + xv[2] + xv[3], scr) * (1.0f / 1024.0f);
    v4f d = xv - m;
    float var = block_sum(d[0]*d[0] + d[1]*d[1] + d[2]*d[2] + d[3]*d[3], scr) * (1.0f / 1024.0f);
    float rs = rsqrtf(var + 1e-5f);
    v4f w4 = ((const v4f*)w)[t], b4 = ((const v4f*)b)[t];
    return d * rs * w4 + b4;
}

__device__ __forceinline__ v4f mixv(v4f n, v4f s, v4f m) { return n * m + s * (1.0f - m); }

__device__ __forceinline__ float dotv(v4f a, v4f x) {
    return fmaf(a[0], x[0], fmaf(a[1], x[1], fmaf(a[2], x[2], a[3] * x[3])));
}

// ---------------- weight row in 16 VGPRs ----------------

struct Row { v4f a, b, c, d; };

__device__ __forceinline__ void row_load(Row& r, const float* p, int lane) {
    const v4f* q = (const v4f*)p;
    r.a = q[lane]; r.b = q[lane + 64]; r.c = q[lane + 128]; r.d = q[lane + 192];
}
__device__ __forceinline__ void row_pin(Row& r) {
    asm volatile("" : "+v"(r.a), "+v"(r.b), "+v"(r.c), "+v"(r.d));
}
__device__ __forceinline__ float row_dot(const Row& r, const v4f* v, int lane) {
    return dotv(r.a, v[lane]) + dotv(r.b, v[lane + 64]) +
           dotv(r.c, v[lane + 128]) + dotv(r.d, v[lane + 192]);
}

// ---------------- coherent (LLC) data ops: relaxed agent scope (sc0sc1) -----

__device__ __forceinline__ void astore_f(float* p, float v) {
    __hip_atomic_store(p, v, __ATOMIC_RELAXED, AG);
}
__device__ __forceinline__ void cload(v4f& d, const float* p) {
    asm volatile("global_load_dwordx4 %0, %1, off sc0 sc1" : "=v"(d) : "v"(p));
}
__device__ __forceinline__ void cwait1(v4f& a) {
    asm volatile("s_waitcnt vmcnt(0)" : "+v"(a));
}
__device__ __forceinline__ void cwait3(v4f& a, v4f& b, v4f& c) {
    asm volatile("s_waitcnt vmcnt(0)" : "+v"(a), "+v"(b), "+v"(c));
}
__device__ __forceinline__ void cwait4(v4f& a, v4f& b, v4f& c, v4f& d) {
    asm volatile("s_waitcnt vmcnt(0)" : "+v"(a), "+v"(b), "+v"(c), "+v"(d));
}

__device__ __forceinline__ u32 ag_ld(u32* p)  { return __hip_atomic_load(p, __ATOMIC_RELAXED, AG); }
__device__ __forceinline__ void ag_st(u32* p, u32 v) { __hip_atomic_store(p, v, __ATOMIC_RELAXED, AG); }

// ---------------- clean-wave-0 leader-release barrier ----------------
// Wave 0 of every block issues NO global loads between f_arrive and f_wait,
// so t0's RMW/poll are pure LLC hops, never queued behind prefetch drains.

__device__ __forceinline__ void f_arrive(u32* ctr, int b) {
    __syncthreads();   // per-wave vmcnt(0) drain: data stores retired to LLC
    if (threadIdx.x == 0)
        __hip_atomic_fetch_add(&ctr[(b & 31) * 32], 1u, __ATOMIC_RELAXED, AG);
}

__device__ __forceinline__ void f_wait(u32* ctr, u32* rel, u32 ev, int b) {
    if (threadIdx.x == 0) {
        if (b == 0) {
            const u32 tgt = ev * (u32)NB;
            for (;;) {
                u32 s = 0;
#pragma unroll
                for (int i = 0; i < 32; ++i) s += ag_ld(&ctr[i * 32]);
                if (s >= tgt) break;
                __builtin_amdgcn_s_sleep(1);
            }
#pragma unroll
            for (int i = 0; i < 8; ++i) ag_st(&rel[i * 32], ev);
        } else {
            while (ag_ld(&rel[(b & 7) * 32]) < ev) __builtin_amdgcn_s_sleep(1);
        }
    }
    __syncthreads();
}

// ---------------- the whole network, one kernel ----------------
// 1024 blocks x 256 threads, 4 blocks/CU exact residency.
// Rows live on waves 1-3 only:
//   w1: kw[b] | fkw[4b], fkw[4b+1] | fvw q0
//   w2: vw[b], ow[b] | fkw[4b+2], fkw[4b+3] | fvw q1
//   w3: rw[b] | frw[b] | fvw q2, q3

__global__ __launch_bounds__(256, 4) void rwkv_all(
    const float* __restrict__ token_embd, const float* __restrict__ state,
    const float* __restrict__ emb_ln_w, const float* __restrict__ emb_ln_b,
    const float* __restrict__ ln1_w, const float* __restrict__ ln1_b,
    const float* __restrict__ ln2_w, const float* __restrict__ ln2_b,
    const float* __restrict__ att_tmk, const float* __restrict__ att_tmv,
    const float* __restrict__ att_tmr, const float* __restrict__ att_tf,
    const float* __restrict__ att_td,
    const float* __restrict__ att_kw, const float* __restrict__ att_vw,
    const float* __restrict__ att_rw, const float* __restrict__ att_ow,
    const float* __restrict__ ffn_tmk, const float* __restrict__ ffn_tmr,
    const float* __restrict__ ffn_kw, const float* __restrict__ ffn_vw,
    const float* __restrict__ ffn_rw,
    const float* __restrict__ out_ln_w, const float* __restrict__ out_ln_b,
    const float* __restrict__ head_w,
    float* __restrict__ logits, float* __restrict__ st_out_base,
    float* __restrict__ ws, u32* __restrict__ syncm) {

    __shared__ v4f s_mix[3][256];
    __shared__ v4f s_x4[256];
    __shared__ v4f s_vec[256];
    __shared__ float scr[4];
    __shared__ float s_red[8];

    const int t = threadIdx.x, lane = t & 63, w = t >> 6, b = blockIdx.x;

    float* xD = ws;             // x after full layer
    float* xB = ws + 1024;      // x after time-mixing
    float* kk = ws + 2048;
    float* vv = ws + 3072;
    float* rr = ws + 4096;
    float* k2 = ws + 5120;      // 4096

    u32* ctr = syncm;           // 32 lines * 32 u32
    u32* rel = syncm + 1024;    // 8 lines

    // ---- encoder LN (redundant per block) ----
    v4f xcur = ((const v4f*)token_embd)[t];
    xcur = ln_vec(xcur, emb_ln_w, emb_ln_b, scr, t);

    // ---- layer-0 prefetch: rA on w1/w2/w3, rB (ow) on w2 ----
    Row rA, rB, rC0, rC1, rD;
    if (w == 1)      row_load(rA, att_kw + (size_t)b * DD, lane);
    else if (w == 2) { row_load(rA, att_vw + (size_t)b * DD, lane);
                       row_load(rB, att_ow + (size_t)b * DD, lane); }
    else if (w == 3) row_load(rA, att_rw + (size_t)b * DD, lane);

    u32 ev = 0;
#pragma unroll 1
    for (int i = 0; i < LL; ++i) {
        const size_t oD = (size_t)i * DD;
        const float* st = state + (size_t)i * 5 * DD;
        float* sto = st_out_base + (size_t)i * 5 * DD;
        const float scale = ((i + 1) % 6 == 0) ? 0.5f : 1.0f;

        // ============== stage A: LN1 + time-mix + {k,v,r} dots ==============
        v4f xv;
        if (i == 0) xv = xcur;
        else { cload(xv, xD + 4 * t); cwait1(xv); }
        s_x4[t] = xv;
        v4f n = ln_vec(xv, ln1_w + oD, ln1_b + oD, scr, t);
        if (b < 256 && t == b) {
            float* p = sto + DD + 4 * b;
            p[0] = n[0]; p[1] = n[1]; p[2] = n[2]; p[3] = n[3];
        }
        {
            v4f sa = ((const v4f*)(st + DD))[t];
            s_mix[0][t] = mixv(n, sa, ((const v4f*)(att_tmk + oD))[t]);
            s_mix[1][t] = mixv(n, sa, ((const v4f*)(att_tmv + oD))[t]);
            s_mix[2][t] = mixv(n, sa, ((const v4f*)(att_tmr + oD))[t]);
        }
        __syncthreads();
        if (w >= 1) {
            float acc = wave_sum(row_dot(rA, &s_mix[w - 1][0], lane));
            if (lane == 0) {
                if (w == 1)      astore_f(kk + b, acc);
                else if (w == 2) astore_f(vv + b, acc);
                else             astore_f(rr + b, 1.0f / (1.0f + expf(-acc)));
            }
        }
        // ---- E1: prefetch fkw rows + frw (waves 1-3 only) ----
        f_arrive(ctr, b);
        __builtin_amdgcn_sched_barrier(0);
        {
            const float* fk = ffn_kw + (size_t)i * FF * DD;
            if (w == 1) { row_load(rC0, fk + (size_t)(4 * b + 0) * DD, lane);
                          row_load(rC1, fk + (size_t)(4 * b + 1) * DD, lane);
                          row_pin(rC0); row_pin(rC1); }
            else if (w == 2) { row_load(rC0, fk + (size_t)(4 * b + 2) * DD, lane);
                               row_load(rC1, fk + (size_t)(4 * b + 3) * DD, lane);
                               row_pin(rC0); row_pin(rC1); }
            else if (w == 3) { row_load(rC0, ffn_rw + (size_t)i * DD * DD + (size_t)b * DD, lane);
                               row_pin(rC0); }
        }
        f_wait(ctr, rel, ++ev, b);

        // ============== stage B: wkv + ow dot + residual =====================
        {
            v4f kx, vx, rx;
            cload(kx, kk + 4 * t); cload(vx, vv + 4 * t); cload(rx, rr + 4 * t);
            cwait3(kx, vx, rx);
            v4f aa = ((const v4f*)(st + 2 * DD))[t];
            v4f bb = ((const v4f*)(st + 3 * DD))[t];
            v4f pp = ((const v4f*)(st + 4 * DD))[t];
            v4f tf = ((const v4f*)(att_tf + oD))[t];
            v4f td = ((const v4f*)(att_td + oD))[t];
            v4f rab, naa, nbb, np2;
#pragma unroll
            for (int c = 0; c < 4; ++c) {
                float kc = kx[c], vc = vx[c];
                float wwc = tf[c] + kc;
                float p = fmaxf(pp[c], wwc);
                float e1 = expf(pp[c] - p), e2 = expf(wwc - p);
                rab[c] = rx[c] * ((e1 * aa[c] + e2 * vc) / (e1 * bb[c] + e2));
                float ww2 = pp[c] + td[c];
                float p2 = fmaxf(ww2, kc);
                float f1 = expf(ww2 - p2), f2 = expf(kc - p2);
                naa[c] = f1 * aa[c] + f2 * vc;
                nbb[c] = f1 * bb[c] + f2;
                np2[c] = p2;
            }
            s_vec[t] = rab;
            if (b < 256 && t == b) {
                float* pa = sto + 2 * DD + 4 * b;
                float* pb = sto + 3 * DD + 4 * b;
                float* pc = sto + 4 * DD + 4 * b;
#pragma unroll
                for (int c = 0; c < 4; ++c) { pa[c] = naa[c]; pb[c] = nbb[c]; pc[c] = np2[c]; }
            }
        }
        __syncthreads();
        if (w == 2) {                      // ow row lives on wave 2
            float acc = wave_sum(row_dot(rB, &s_vec[0], lane));
            if (lane == 0) astore_f(xB + b, ((float*)s_x4)[b] + acc);
        }
        // ---- E2: prefetch fvw quarters (w1:q0, w2:q1, w3:q2+q3) ----
        f_arrive(ctr, b);
        __builtin_amdgcn_sched_barrier(0);
        {
            const float* fv = ffn_vw + (size_t)i * DD * FF + (size_t)b * FF;
            if (w == 1) { row_load(rD, fv, lane); row_pin(rD); }
            else if (w == 2) { row_load(rD, fv + 1024, lane); row_pin(rD); }
            else if (w == 3) { row_load(rD, fv + 2048, lane);
                               row_load(rC1, fv + 3072, lane);
                               row_pin(rD); row_pin(rC1); }
        }
        f_wait(ctr, rel, ++ev, b);

        // ============== stage C: LN2 + chan-mix + fkw/frw dots ===============
        cload(xv, xB + 4 * t); cwait1(xv);
        s_x4[t] = xv;
        n = ln_vec(xv, ln2_w + oD, ln2_b + oD, scr, t);
        if (b < 256 && t == b) {
            float* p = sto + 4 * b;
            p[0] = n[0]; p[1] = n[1]; p[2] = n[2]; p[3] = n[3];
        }
        {
            v4f sf = ((const v4f*)st)[t];
            s_mix[0][t] = mixv(n, sf, ((const v4f*)(ffn_tmk + oD))[t]);
            s_mix[1][t] = mixv(n, sf, ((const v4f*)(ffn_tmr + oD))[t]);
        }
        __syncthreads();
        if (w == 1 || w == 2) {
            float a0 = wave_sum(row_dot(rC0, &s_mix[0][0], lane));
            float a1 = wave_sum(row_dot(rC1, &s_mix[0][0], lane));
            if (lane == 0) {
                int base = 4 * b + (w == 1 ? 0 : 2);
                float r0 = fmaxf(a0, 0.f), r1 = fmaxf(a1, 0.f);
                astore_f(k2 + base, r0 * r0);
                astore_f(k2 + base + 1, r1 * r1);
            }
        } else if (w == 3) {
            float acc = wave_sum(row_dot(rC0, &s_mix[1][0], lane));
            if (lane == 0) s_red[4] = 1.0f / (1.0f + expf(-acc));   // r2[b], block-local
        }
        // ---- E3: prefetch next-layer k/v/r rows (waves 1-3) ----
        f_arrive(ctr, b);
        __builtin_amdgcn_sched_barrier(0);
        if (i + 1 < LL && w >= 1) {
            const float* p = (w == 1 ? att_kw : w == 2 ? att_vw : att_rw)
                             + (size_t)(i + 1) * DD * DD + (size_t)b * DD;
            row_load(rA, p, lane);
            row_pin(rA);
        }
        f_wait(ctr, rel, ++ev, b);

        // ============== stage D: fvw dots + gated residual + rescale =========
        if (w == 1 || w == 2) {
            v4f q0, q1, q2, q3;
            const float* kq = k2 + (w - 1) * 1024;
            cload(q0, kq + lane * 4);       cload(q1, kq + (lane + 64) * 4);
            cload(q2, kq + (lane + 128) * 4); cload(q3, kq + (lane + 192) * 4);
            cwait4(q0, q1, q2, q3);
            float acc = dotv(rD.a, q0) + dotv(rD.b, q1) + dotv(rD.c, q2) + dotv(rD.d, q3);
            acc = wave_sum(acc);
            if (lane == 0) s_red[w - 1] = acc;
        } else if (w == 3) {
            v4f q0, q1, q2, q3, p0, p1, p2, p3;
            const float* kq2 = k2 + 2048;
            const float* kq3 = k2 + 3072;
            cload(q0, kq2 + lane * 4);       cload(q1, kq2 + (lane + 64) * 4);
            cload(q2, kq2 + (lane + 128) * 4); cload(q3, kq2 + (lane + 192) * 4);
            cload(p0, kq3 + lane * 4);       cload(p1, kq3 + (lane + 64) * 4);
            cload(p2, kq3 + (lane + 128) * 4); cload(p3, kq3 + (lane + 192) * 4);
            cwait4(q0, q1, q2, q3);
            cwait4(p0, p1, p2, p3);
            float a2 = dotv(rD.a, q0) + dotv(rD.b, q1) + dotv(rD.c, q2) + dotv(rD.d, q3);
            float a3 = dotv(rC1.a, p0) + dotv(rC1.b, p1) + dotv(rC1.c, p2) + dotv(rC1.d, p3);
            a2 = wave_sum(a2); a3 = wave_sum(a3);
            if (lane == 0) { s_red[2] = a2; s_red[3] = a3; }
        }
        __syncthreads();
        if (t == 0) {
            float dsum = s_red[0] + s_red[1] + s_red[2] + s_red[3];
            astore_f(xD + b, (((float*)s_x4)[b] + s_red[4] * dsum) * scale);
        }
        // ---- E4: prefetch next-layer ow row (wave 2) ----
        f_arrive(ctr, b);
        __builtin_amdgcn_sched_barrier(0);
        if (i + 1 < LL && w == 2) {
            row_load(rB, att_ow + (size_t)(i + 1) * DD * DD + (size_t)b * DD, lane);
            row_pin(rB);
        }
        f_wait(ctr, rel, ++ev, b);
    }

    // ================= head: LN_out + 50277x1024 GEMV ========================
    v4f xh;
    cload(xh, xD + 4 * t); cwait1(xh);
    v4f nh = ln_vec(xh, out_ln_w, out_ln_b, scr, t);
    s_vec[t] = nh;
    __syncthreads();
#pragma unroll 1
    for (int j = 0; j < 13; ++j) {
        int row = j * 4096 + 4 * b + w;
        if (row < VV) {
            Row rh;
            row_load(rh, head_w + (size_t)row * DD, lane);
            float acc = wave_sum(row_dot(rh, &s_vec[0], lane));
            if (lane == 0) logits[row] = acc;
        }
    }
}

// ---------------- launch ----------------

extern "C" void kernel_launch(void* const* d_in, const int* in_sizes, int n_in,
                              void* d_out, int out_size, void* d_ws, size_t ws_size,
                              hipStream_t stream) {
    const float* token_embd = (const float*)d_in[0];
    const float* state      = (const float*)d_in[1];
    const float* emb_ln_w   = (const float*)d_in[2];
    const float* emb_ln_b   = (const float*)d_in[3];
    const float* ln1_w      = (const float*)d_in[4];
    const float* ln1_b      = (const float*)d_in[5];
    const float* ln2_w      = (const float*)d_in[6];
    const float* ln2_b      = (const float*)d_in[7];
    const float* att_tmk    = (const float*)d_in[8];
    const float* att_tmv    = (const float*)d_in[9];
    const float* att_tmr    = (const float*)d_in[10];
    const float* att_tf     = (const float*)d_in[11];
    const float* att_td     = (const float*)d_in[12];
    const float* att_kw     = (const float*)d_in[13];
    const float* att_vw     = (const float*)d_in[14];
    const float* att_rw     = (const float*)d_in[15];
    const float* att_ow     = (const float*)d_in[16];
    const float* ffn_tmk    = (const float*)d_in[17];
    const float* ffn_tmr    = (const float*)d_in[18];
    const float* ffn_kw     = (const float*)d_in[19];
    const float* ffn_vw     = (const float*)d_in[20];
    const float* ffn_rw     = (const float*)d_in[21];
    const float* out_ln_w   = (const float*)d_in[22];
    const float* out_ln_b   = (const float*)d_in[23];
    const float* head_w     = (const float*)d_in[24];

    float* logits = (float*)d_out;
    float* st_out_base = (float*)d_out + VV;

    float* ws = (float*)d_ws;
    u32* syncm = (u32*)(ws + 9216);    // 1280 u32 used; zero 8KB

    hipMemsetAsync(syncm, 0, 8192, stream);

    rwkv_all<<<NB, 256, 0, stream>>>(
        token_embd, state, emb_ln_w, emb_ln_b, ln1_w, ln1_b, ln2_w, ln2_b,
        att_tmk, att_tmv, att_tmr, att_tf, att_td,
        att_kw, att_vw, att_rw, att_ow,
        ffn_tmk, ffn_tmr, ffn_kw, ffn_vw, ffn_rw,
        out_ln_w, out_ln_b, head_w,
        logits, st_out_base, ws, syncm);
}

// Round 7
// 722.482 us; speedup vs baseline: 2.4500x; 2.4500x over previous
//
#include <hip/hip_runtime.h>

#define DD 1024
#define FF 4096
#define LL 24
#define VV 50277
#define PFB 256

typedef float v4f __attribute__((ext_vector_type(4)));

// ---------------- reductions ----------------

__device__ __forceinline__ float wave_sum(float v) {
#pragma unroll
    for (int o = 32; o > 0; o >>= 1) v += __shfl_xor(v, o, 64);
    return v;
}

__device__ __forceinline__ float block_sum(float v, float* scr) {
    v = wave_sum(v);
    int w = threadIdx.x >> 6;
    __syncthreads();
    if ((threadIdx.x & 63) == 0) scr[w] = v;
    __syncthreads();
    return scr[0] + scr[1] + scr[2] + scr[3];
}

__device__ __forceinline__ v4f ln_vec(v4f xv, const float* __restrict__ w,
                                      const float* __restrict__ b, float* scr, int t) {
    float m = block_sum(xv[0] + xv[1] + xv[2] + xv[3], scr) * (1.0f / 1024.0f);
    v4f d = xv - m;
    float var = block_sum(d[0]*d[0] + d[1]*d[1] + d[2]*d[2] + d[3]*d[3], scr) * (1.0f / 1024.0f);
    float rs = rsqrtf(var + 1e-5f);
    v4f w4 = ((const v4f*)w)[t], b4 = ((const v4f*)b)[t];
    return d * rs * w4 + b4;
}

__device__ __forceinline__ v4f mixv(v4f n, v4f s, v4f m) { return n * m + s * (1.0f - m); }

__device__ __forceinline__ float dotv(v4f a, v4f x) {
    return fmaf(a[0], x[0], fmaf(a[1], x[1], fmaf(a[2], x[2], a[3] * x[3])));
}

struct Row { v4f a, b, c, d; };

__device__ __forceinline__ void row_load(Row& r, const float* p, int lane) {
    const v4f* q = (const v4f*)p;
    r.a = q[lane]; r.b = q[lane + 64]; r.c = q[lane + 128]; r.d = q[lane + 192];
}
__device__ __forceinline__ float row_dot(const Row& r, const v4f* v, int lane) {
    return dotv(r.a, v[lane]) + dotv(r.b, v[lane + 64]) +
           dotv(r.c, v[lane + 128]) + dotv(r.d, v[lane + 192]);
}

// ---------------- LLC prefetch: stream region into Infinity Cache ----------
// pb in [0,PFB); contiguous chunk per block; 8 loads in flight per thread.

__device__ __forceinline__ void pf_region(const float* p, int nvec, int pb, int t) {
    if (p == nullptr || nvec <= 0) return;
    const v4f* q = (const v4f*)p;
    int chunk = (nvec + PFB - 1) / PFB;
    int lo = pb * chunk;
    int end = lo + chunk; if (end > nvec) end = nvec;
    int i = lo + t;
    v4f a0 = {0,0,0,0}, a1 = a0, a2 = a0, a3 = a0, a4 = a0, a5 = a0, a6 = a0, a7 = a0;
    for (; i + 1792 < end; i += 2048) {
        v4f t0 = q[i],        t1 = q[i + 256],  t2 = q[i + 512],  t3 = q[i + 768];
        v4f t4 = q[i + 1024], t5 = q[i + 1280], t6 = q[i + 1536], t7 = q[i + 1792];
        a0 += t0; a1 += t1; a2 += t2; a3 += t3;
        a4 += t4; a5 += t5; a6 += t6; a7 += t7;
    }
    for (; i < end; i += 256) a0 += q[i];
    a0 = (a0 + a1) + (a2 + a3) + ((a4 + a5) + (a6 + a7));
    asm volatile("" :: "v"(a0));   // keep loads live (rule #17)
}

// ---------------- K1: [enc LN +] LN1 + time-mix + {kw,vw,rw} GEMV ----------
// grid = PFB + 768

__global__ __launch_bounds__(256) void k1_timemix(
    const float* __restrict__ xin, const float* __restrict__ st,
    const float* __restrict__ enc_w, const float* __restrict__ enc_b,
    const float* __restrict__ l1w, const float* __restrict__ l1b,
    const float* __restrict__ tmk, const float* __restrict__ tmv,
    const float* __restrict__ tmr,
    const float* __restrict__ kw, const float* __restrict__ vw,
    const float* __restrict__ rw,
    float* __restrict__ kk, float* __restrict__ vv, float* __restrict__ rr,
    float* __restrict__ x0out, float* __restrict__ st_out,
    const float* pfa, int na, const float* pfb, int nb) {
    const int t = threadIdx.x;
    int b = blockIdx.x;
    if (b < PFB) { pf_region(pfa, na, b, t); pf_region(pfb, nb, b, t); return; }
    b -= PFB;
    __shared__ __align__(16) float s_k[DD], s_v[DD], s_r[DD];
    __shared__ float scr[4];
    const int lane = t & 63, w = t >> 6;

    v4f xv = ((const v4f*)xin)[t];
    if (enc_w) xv = ln_vec(xv, enc_w, enc_b, scr, t);   // x0 = LN(token_embd)
    if (x0out && b == 0) ((v4f*)x0out)[t] = xv;         // publish x0 for k2/k3
    v4f n = ln_vec(xv, l1w, l1b, scr, t);
    if (b == 0) ((v4f*)(st_out + DD))[t] = n;           // new_st[1] = xn
    {
        v4f sa = ((const v4f*)(st + DD))[t];
        ((v4f*)s_k)[t] = mixv(n, sa, ((const v4f*)tmk)[t]);
        ((v4f*)s_v)[t] = mixv(n, sa, ((const v4f*)tmv)[t]);
        ((v4f*)s_r)[t] = mixv(n, sa, ((const v4f*)tmr)[t]);
    }
    __syncthreads();

    const int ridx = b * 4 + w, m = ridx >> 10, row = ridx & 1023;
    Row W;
    row_load(W, (m == 0 ? kw : m == 1 ? vw : rw) + (size_t)row * DD, lane);
    const v4f* vec = (const v4f*)(m == 0 ? s_k : m == 1 ? s_v : s_r);
    float acc = wave_sum(row_dot(W, vec, lane));
    if (lane == 0) {
        if (m == 0)      kk[row] = acc;
        else if (m == 1) vv[row] = acc;
        else             rr[row] = 1.0f / (1.0f + expf(-acc));
    }
}

// ---------------- K2: wkv elementwise + state write + ow GEMV + residual ----
// grid = PFB + 256

__global__ __launch_bounds__(256) void k2_wkv_out(
    const float* __restrict__ st, const float* __restrict__ tf,
    const float* __restrict__ td,
    const float* __restrict__ kk, const float* __restrict__ vv,
    const float* __restrict__ rr, const float* __restrict__ ow,
    float* __restrict__ x, float* __restrict__ st_out,
    const float* pfa, int na, const float* pfb, int nb) {
    const int t = threadIdx.x;
    int b = blockIdx.x;
    if (b < PFB) { pf_region(pfa, na, b, t); pf_region(pfb, nb, b, t); return; }
    b -= PFB;
    __shared__ __align__(16) float rab[DD];
    const int lane = t & 63, w = t >> 6;

    {
        v4f kx = ((const v4f*)kk)[t];
        v4f vx = ((const v4f*)vv)[t];
        v4f rx = ((const v4f*)rr)[t];
        v4f aa = ((const v4f*)(st + 2 * DD))[t];
        v4f bb = ((const v4f*)(st + 3 * DD))[t];
        v4f pp = ((const v4f*)(st + 4 * DD))[t];
        v4f tf4 = ((const v4f*)tf)[t];
        v4f td4 = ((const v4f*)td)[t];
        v4f rb, naa, nbb, np2;
#pragma unroll
        for (int c = 0; c < 4; ++c) {
            float kc = kx[c], vc = vx[c];
            float wwc = tf4[c] + kc;
            float p = fmaxf(pp[c], wwc);
            float e1 = expf(pp[c] - p), e2 = expf(wwc - p);
            rb[c] = rx[c] * ((e1 * aa[c] + e2 * vc) / (e1 * bb[c] + e2));
            float ww2 = pp[c] + td4[c];
            float p2 = fmaxf(ww2, kc);
            float f1 = expf(ww2 - p2), f2 = expf(kc - p2);
            naa[c] = f1 * aa[c] + f2 * vc;
            nbb[c] = f1 * bb[c] + f2;
            np2[c] = p2;
        }
        ((v4f*)rab)[t] = rb;
        if (b == 0) {
            ((v4f*)(st_out + 2 * DD))[t] = naa;
            ((v4f*)(st_out + 3 * DD))[t] = nbb;
            ((v4f*)(st_out + 4 * DD))[t] = np2;
        }
    }
    __syncthreads();

    const int row = b * 4 + w;
    Row W;
    row_load(W, ow + (size_t)row * DD, lane);
    float acc = wave_sum(row_dot(W, (const v4f*)rab, lane));
    if (lane == 0) x[row] += acc;    // residual
}

// ---------------- K3: LN2 + chan-mix + {fkw,frw} GEMV (relu^2 / sigmoid) ----
// grid = PFB + 1280 (5120 rows)

__global__ __launch_bounds__(256) void k3_ffn_kr(
    const float* __restrict__ x, const float* __restrict__ st,
    const float* __restrict__ l2w, const float* __restrict__ l2b,
    const float* __restrict__ ftmk, const float* __restrict__ ftmr,
    const float* __restrict__ fkw, const float* __restrict__ frw,
    float* __restrict__ k2, float* __restrict__ r2, float* __restrict__ st_out,
    const float* pfa, int na, const float* pfb, int nb) {
    const int t = threadIdx.x;
    int b = blockIdx.x;
    if (b < PFB) { pf_region(pfa, na, b, t); pf_region(pfb, nb, b, t); return; }
    b -= PFB;
    __shared__ __align__(16) float s_k[DD], s_r[DD];
    __shared__ float scr[4];
    const int lane = t & 63, w = t >> 6;

    v4f xv = ((const v4f*)x)[t];
    v4f n = ln_vec(xv, l2w, l2b, scr, t);
    if (b == 0) ((v4f*)st_out)[t] = n;                  // new_st[0] = xn2
    {
        v4f sf = ((const v4f*)st)[t];
        ((v4f*)s_k)[t] = mixv(n, sf, ((const v4f*)ftmk)[t]);
        ((v4f*)s_r)[t] = mixv(n, sf, ((const v4f*)ftmr)[t]);
    }
    __syncthreads();

    const int ridx = b * 4 + w;
    const float* Wp;
    const v4f* vec;
    if (ridx < FF) { Wp = fkw + (size_t)ridx * DD; vec = (const v4f*)s_k; }
    else           { Wp = frw + (size_t)(ridx - FF) * DD; vec = (const v4f*)s_r; }
    Row W;
    row_load(W, Wp, lane);
    float acc = wave_sum(row_dot(W, vec, lane));
    if (lane == 0) {
        if (ridx < FF) { float rl = fmaxf(acc, 0.f); k2[ridx] = rl * rl; }
        else           r2[ridx - FF] = 1.0f / (1.0f + expf(-acc));
    }
}

// ---------------- K4: fvw GEMV + gated residual + rescale -------------------
// grid = PFB + 256

__global__ __launch_bounds__(256) void k4_ffn_v(
    const float* __restrict__ fvw, const float* __restrict__ k2,
    const float* __restrict__ r2, float* __restrict__ x, float scale,
    const float* pfa, int na, const float* pfb, int nb) {
    const int t = threadIdx.x;
    int b = blockIdx.x;
    if (b < PFB) { pf_region(pfa, na, b, t); pf_region(pfb, nb, b, t); return; }
    b -= PFB;
    __shared__ __align__(16) float k2s[FF];
    const int lane = t & 63, w = t >> 6;
#pragma unroll
    for (int j = 0; j < 4; ++j)
        ((v4f*)k2s)[t + 256 * j] = ((const v4f*)k2)[t + 256 * j];
    __syncthreads();

    const int row = b * 4 + w;
    const v4f* W4 = (const v4f*)(fvw + (size_t)row * FF);
    const v4f* v4 = (const v4f*)k2s;
    float acc = 0.f;
#pragma unroll
    for (int j = 0; j < 16; ++j) {
        v4f a = W4[lane + 64 * j];
        v4f bx = v4[lane + 64 * j];
        acc = fmaf(a[0], bx[0], fmaf(a[1], bx[1], fmaf(a[2], bx[2], fmaf(a[3], bx[3], acc))));
    }
    acc = wave_sum(acc);
    if (lane == 0) x[row] = (x[row] + r2[row] * acc) * scale;
}

// ---------------- head: folded final LN + 50277x1024 GEMV -------------------

__global__ __launch_bounds__(256) void k_head(const float* __restrict__ head_w,
                                              const float* __restrict__ x,
                                              const float* __restrict__ olw,
                                              const float* __restrict__ olb,
                                              float* __restrict__ logits) {
    __shared__ __align__(16) float xs[DD];
    __shared__ float scr[4];
    const int t = threadIdx.x, lane = t & 63, w = t >> 6;
    const int row = blockIdx.x * 4 + w;
    Row W;
    if (row < VV) row_load(W, head_w + (size_t)row * DD, lane);
    v4f xv = ((const v4f*)x)[t];
    v4f nx = ln_vec(xv, olw, olb, scr, t);
    ((v4f*)xs)[t] = nx;
    __syncthreads();
    if (row < VV) {
        float acc = wave_sum(row_dot(W, (const v4f*)xs, lane));
        if (lane == 0) logits[row] = acc;
    }
}

// ---------------- launch ----------------

extern "C" void kernel_launch(void* const* d_in, const int* in_sizes, int n_in,
                              void* d_out, int out_size, void* d_ws, size_t ws_size,
                              hipStream_t stream) {
    const float* token_embd = (const float*)d_in[0];
    const float* state      = (const float*)d_in[1];
    const float* emb_ln_w   = (const float*)d_in[2];
    const float* emb_ln_b   = (const float*)d_in[3];
    const float* ln1_w      = (const float*)d_in[4];
    const float* ln1_b      = (const float*)d_in[5];
    const float* ln2_w      = (const float*)d_in[6];
    const float* ln2_b      = (const float*)d_in[7];
    const float* att_tmk    = (const float*)d_in[8];
    const float* att_tmv    = (const float*)d_in[9];
    const float* att_tmr    = (const float*)d_in[10];
    const float* att_tf     = (const float*)d_in[11];
    const float* att_td     = (const float*)d_in[12];
    const float* att_kw     = (const float*)d_in[13];
    const float* att_vw     = (const float*)d_in[14];
    const float* att_rw     = (const float*)d_in[15];
    const float* att_ow     = (const float*)d_in[16];
    const float* ffn_tmk    = (const float*)d_in[17];
    const float* ffn_tmr    = (const float*)d_in[18];
    const float* ffn_kw     = (const float*)d_in[19];
    const float* ffn_vw     = (const float*)d_in[20];
    const float* ffn_rw     = (const float*)d_in[21];
    const float* out_ln_w   = (const float*)d_in[22];
    const float* out_ln_b   = (const float*)d_in[23];
    const float* head_w     = (const float*)d_in[24];

    float* logits = (float*)d_out;
    float* st_out_base = (float*)d_out + VV;

    float* ws  = (float*)d_ws;
    float* x   = ws;             // 1024
    float* kk  = ws + 1024;
    float* vv  = ws + 2048;
    float* rr  = ws + 3072;
    float* k2b = ws + 4096;      // 4096
    float* r2b = ws + 8192;      // 1024

    const int V_D   = DD * DD / 4;       // 4 MB matrix  = 262144 vec4
    const int V_FKH = FF * DD / 8;       // 8 MB (fkw/2) = 524288 vec4

    for (int i = 0; i < LL; ++i) {
        const float* st = state + (size_t)i * 5 * DD;
        float* sto = st_out_base + (size_t)i * 5 * DD;
        const float* kw_i  = att_kw + (size_t)i * DD * DD;
        const float* vw_i  = att_vw + (size_t)i * DD * DD;
        const float* rw_i  = att_rw + (size_t)i * DD * DD;
        const float* ow_i  = att_ow + (size_t)i * DD * DD;
        const float* fkw_i = ffn_kw + (size_t)i * FF * DD;
        const float* fvw_i = ffn_vw + (size_t)i * DD * FF;
        const float* frw_i = ffn_rw + (size_t)i * DD * DD;
        const bool last = (i == LL - 1);

        // K1 prefetches: ow(i), first half of fkw(i)
        k1_timemix<<<PFB + 768, 256, 0, stream>>>(
            (i == 0) ? token_embd : x, st,
            (i == 0) ? emb_ln_w : nullptr, (i == 0) ? emb_ln_b : nullptr,
            ln1_w + i * DD, ln1_b + i * DD,
            att_tmk + i * DD, att_tmv + i * DD, att_tmr + i * DD,
            kw_i, vw_i, rw_i, kk, vv, rr,
            (i == 0) ? x : nullptr, sto,
            ow_i, V_D, fkw_i, V_FKH);

        // K2 prefetches: second half of fkw(i), frw(i)
        k2_wkv_out<<<PFB + 256, 256, 0, stream>>>(
            st, att_tf + i * DD, att_td + i * DD, kk, vv, rr, ow_i, x, sto,
            fkw_i + (size_t)FF * DD / 2, V_FKH, frw_i, V_D);

        // K3 prefetches: fvw(i), rw(i+1)
        k3_ffn_kr<<<PFB + 1280, 256, 0, stream>>>(
            x, st, ln2_w + i * DD, ln2_b + i * DD,
            ffn_tmk + i * DD, ffn_tmr + i * DD, fkw_i, frw_i,
            k2b, r2b, sto,
            fvw_i, 2 * V_FKH,
            last ? nullptr : rw_i + DD * DD, last ? 0 : V_D);

        // K4 prefetches: kw(i+1), vw(i+1)
        float scale = ((i + 1) % 6 == 0) ? 0.5f : 1.0f;
        k4_ffn_v<<<PFB + 256, 256, 0, stream>>>(
            fvw_i, k2b, r2b, x, scale,
            last ? nullptr : kw_i + DD * DD, last ? 0 : V_D,
            last ? nullptr : vw_i + DD * DD, last ? 0 : V_D);
    }

    k_head<<<(VV + 3) / 4, 256, 0, stream>>>(head_w, x, out_ln_w, out_ln_b, logits);
}